// Round 4
// baseline (327.041 us; speedup 1.0000x reference)
//
#include <hip/hip_runtime.h>
#include <hip/hip_fp16.h>

#define FEAT1 64
#define FEAT2 16
#define RBINS 6250      // bins per LDS range (25 KB)
#define NCHUNK 25       // edge chunks

// Pass A: privatized histograms. grid = NCHUNK x (2*nrangeSide) blocks.
// ranges [0,nrangeSide) histogram src ids; [nrangeSide, 2*nrangeSide) histogram dst ids.
__global__ __launch_bounds__(256) void hist_part_kernel(const int* __restrict__ src,
                                                        const int* __restrict__ dst,
                                                        int* __restrict__ partialS,
                                                        int* __restrict__ partialD,
                                                        int E, int N, int chunkE, int nrangeSide) {
    __shared__ int h[RBINS];
    int tid = threadIdx.x;
    int range = blockIdx.x % (2 * nrangeSide);
    int chunk = blockIdx.x / (2 * nrangeSide);
    bool isDst = range >= nrangeSide;
    int lo = (range % nrangeSide) * RBINS;
    for (int i = tid; i < RBINS; i += 256) h[i] = 0;
    __syncthreads();
    const int* ids = isDst ? dst : src;
    int e_end = min(E, (chunk + 1) * chunkE);
    for (int e = chunk * chunkE + tid; e < e_end; e += 256) {
        unsigned rel = (unsigned)(ids[e] - lo);
        if (rel < RBINS) atomicAdd(&h[rel], 1);
    }
    __syncthreads();
    int* outp = (isDst ? partialD : partialS) + (size_t)chunk * N + lo;
    int lim = min(RBINS, N - lo);
    for (int i = tid; i < lim; i += 256) outp[i] = h[i];
}

// Pass B: reduce partials -> norms + hist_dst; rewrite partialD to exclusive per-chunk base.
__global__ __launch_bounds__(256) void reduce_part_kernel(const int* __restrict__ partialS,
                                                          int* __restrict__ partialD,
                                                          int* __restrict__ hist_dst,
                                                          float* __restrict__ norm_src,
                                                          float* __restrict__ norm_dst,
                                                          int N, int nchunk) {
    int b = blockIdx.x * blockDim.x + threadIdx.x;
    if (b >= N) return;
    int sumS = 0;
    for (int c = 0; c < nchunk; c++) sumS += partialS[(size_t)c * N + b];
    norm_src[b] = rsqrtf(fmaxf((float)sumS, 1.0f));
    int run = 0;
    for (int c = 0; c < nchunk; c++) {
        int t = partialD[(size_t)c * N + b];
        partialD[(size_t)c * N + b] = run;
        run += t;
    }
    hist_dst[b] = run;
    norm_dst[b] = rsqrtf(fmaxf((float)run, 1.0f));
}

// exclusive scan of hist_dst -> offs (N <= 256*256)
__global__ __launch_bounds__(256) void scan1_kernel(const int* __restrict__ hist, int* offs,
                                                    int* partials, int N) {
    __shared__ int s[256];
    int tid = threadIdx.x;
    int i = blockIdx.x * 256 + tid;
    int v = (i < N) ? hist[i] : 0;
    s[tid] = v;
    __syncthreads();
    for (int off = 1; off < 256; off <<= 1) {
        int t = (tid >= off) ? s[tid - off] : 0;
        __syncthreads();
        s[tid] += t;
        __syncthreads();
    }
    if (i < N) offs[i] = s[tid] - v;
    if (tid == 255) partials[blockIdx.x] = s[255];
}

__global__ __launch_bounds__(256) void scan2_kernel(int* partials, int nb) {
    __shared__ int s[256];
    int tid = threadIdx.x;
    int v = (tid < nb) ? partials[tid] : 0;
    s[tid] = v;
    __syncthreads();
    for (int off = 1; off < 256; off <<= 1) {
        int t = (tid >= off) ? s[tid - off] : 0;
        __syncthreads();
        s[tid] += t;
        __syncthreads();
    }
    if (tid < nb) partials[tid] = s[tid] - v;
}

__global__ void scan3_kernel(int* offs, const int* __restrict__ partials, int N) {
    int i = blockIdx.x * blockDim.x + threadIdx.x;
    if (i < N) offs[i] += partials[i >> 8];
}

// Pass D: reorder with LDS cursors (no global atomics). grid = NCHUNK x nrangeSide.
__global__ __launch_bounds__(256) void reorder_kernel(const int* __restrict__ src,
                                                      const int* __restrict__ dst,
                                                      const int* __restrict__ offs,
                                                      const int* __restrict__ partialD,
                                                      int* __restrict__ sorted_src,
                                                      int E, int N, int chunkE, int nrangeSide) {
    __shared__ int cur[RBINS];
    int tid = threadIdx.x;
    int range = blockIdx.x % nrangeSide;
    int chunk = blockIdx.x / nrangeSide;
    int lo = range * RBINS;
    int lim = min(RBINS, N - lo);
    for (int i = tid; i < lim; i += 256) {
        int b = lo + i;
        cur[i] = offs[b] + partialD[(size_t)chunk * N + b];
    }
    __syncthreads();
    int e_end = min(E, (chunk + 1) * chunkE);
    for (int e = chunk * chunkE + tid; e < e_end; e += 256) {
        unsigned rel = (unsigned)(dst[e] - lo);
        if (rel < RBINS) {
            int pos = atomicAdd(&cur[rel], 1);
            sorted_src[pos] = src[e];
        }
    }
}

// h1[row][c] = half((sum_k X[row][k]*W1[k][c]) * norm_src[row]); 16 rows/block
__global__ __launch_bounds__(256) void gemm1_kernel(const float* __restrict__ X,
                                                    const float* __restrict__ W1,
                                                    const float* __restrict__ norm_src,
                                                    __half* __restrict__ h1, int N) {
    __shared__ float sW[64 * 64];
    __shared__ float sX[16][64];
    int tid = threadIdx.x;
    int c = tid & 63, rs = tid >> 6;  // rs 0..3
    int row0 = blockIdx.x * 16;
    for (int i = tid; i < 64 * 64; i += 256) sW[i] = W1[i];
#pragma unroll
    for (int j = 0; j < 4; j++) {
        int r = rs + 4 * j;
        int row = row0 + r;
        sX[r][c] = (row < N) ? X[(size_t)row * 64 + c] : 0.f;
    }
    __syncthreads();
    float acc[4] = {0.f, 0.f, 0.f, 0.f};
#pragma unroll
    for (int k = 0; k < 64; k++) {
        float w = sW[k * 64 + c];
#pragma unroll
        for (int j = 0; j < 4; j++) acc[j] += sX[rs + 4 * j][k] * w;
    }
#pragma unroll
    for (int j = 0; j < 4; j++) {
        int row = row0 + rs + 4 * j;
        if (row < N) h1[(size_t)row * 64 + c] = __float2half(acc[j] * norm_src[row]);
    }
}

// gather-aggregate layer1 (fp16 rows, 4 edges/iter), fuse norm_dst+b1+relu
__global__ __launch_bounds__(256) void agg1_kernel(const __half* __restrict__ h1,
                                                   const int* __restrict__ sorted_src,
                                                   const int* __restrict__ offs,
                                                   const int* __restrict__ cnt,
                                                   const float* __restrict__ norm_dst,
                                                   const float* __restrict__ b1,
                                                   __half* __restrict__ t1, int N) {
    int tid = threadIdx.x;
    int row = blockIdx.x * 4 + (tid >> 6);
    if (row >= N) return;
    int lane = tid & 63;
    int e_off = lane >> 4;   // 0..3
    int fg = lane & 15;      // feats 4fg..4fg+3
    int start = offs[row], c = cnt[row];
    float4 acc = make_float4(0.f, 0.f, 0.f, 0.f);
    for (int j = 0; j < c; j += 4) {
        int je = j + e_off;
        if (je < c) {
            int s = sorted_src[start + je];
            uint2 u = ((const uint2*)(h1 + (size_t)s * 64))[fg];
            __half2 p0 = *reinterpret_cast<__half2*>(&u.x);
            __half2 p1 = *reinterpret_cast<__half2*>(&u.y);
            float2 f0 = __half22float2(p0), f1 = __half22float2(p1);
            acc.x += f0.x; acc.y += f0.y; acc.z += f1.x; acc.w += f1.y;
        }
    }
#pragma unroll
    for (int m = 16; m <= 32; m <<= 1) {
        acc.x += __shfl_xor(acc.x, m);
        acc.y += __shfl_xor(acc.y, m);
        acc.z += __shfl_xor(acc.z, m);
        acc.w += __shfl_xor(acc.w, m);
    }
    if (e_off == 0) {
        float nd = norm_dst[row];
        int f0 = fg * 4;
        float r0 = fmaxf(acc.x * nd + b1[f0 + 0], 0.f);
        float r1 = fmaxf(acc.y * nd + b1[f0 + 1], 0.f);
        float r2 = fmaxf(acc.z * nd + b1[f0 + 2], 0.f);
        float r3 = fmaxf(acc.w * nd + b1[f0 + 3], 0.f);
        __half2 o0 = __floats2half2_rn(r0, r1);
        __half2 o1 = __floats2half2_rn(r2, r3);
        uint2 u;
        u.x = *reinterpret_cast<unsigned int*>(&o0);
        u.y = *reinterpret_cast<unsigned int*>(&o1);
        ((uint2*)(t1 + (size_t)row * 64))[fg] = u;
    }
}

// h2[row][c] = half((sum_k t1[row][k]*W2[k][c]) * norm_src[row])
__global__ __launch_bounds__(256) void gemm2_kernel(const __half* __restrict__ t1,
                                                    const float* __restrict__ W2,
                                                    const float* __restrict__ norm_src,
                                                    __half* __restrict__ h2, int N) {
    __shared__ float sW[64 * 16];
    __shared__ float sT[16][65];
    int tid = threadIdx.x;
    int row0 = blockIdx.x * 16;
    for (int i = tid; i < 64 * 16; i += 256) sW[i] = W2[i];
    for (int l = tid; l < 16 * 32; l += 256) {
        int rr = l >> 5, kp = l & 31;
        int row = row0 + rr;
        float2 v = make_float2(0.f, 0.f);
        if (row < N) {
            __half2 h = ((const __half2*)(t1 + (size_t)row * 64))[kp];
            v = __half22float2(h);
        }
        sT[rr][kp * 2] = v.x;
        sT[rr][kp * 2 + 1] = v.y;
    }
    __syncthreads();
    int r = tid >> 4, c = tid & 15;
    int row = row0 + r;
    if (row < N) {
        float acc = 0.f;
#pragma unroll
        for (int k = 0; k < 64; k++) acc += sT[r][k] * sW[k * 16 + c];
        h2[(size_t)row * 16 + c] = __float2half(acc * norm_src[row]);
    }
}

// gather-aggregate layer2 (8 edges/iter) + epilogue
__global__ __launch_bounds__(256) void agg2_kernel(const __half* __restrict__ h2,
                                                   const int* __restrict__ sorted_src,
                                                   const int* __restrict__ offs,
                                                   const int* __restrict__ cnt,
                                                   const float* __restrict__ norm_dst,
                                                   const float* __restrict__ b2,
                                                   float* __restrict__ out, int N) {
    int tid = threadIdx.x;
    int row = blockIdx.x * 4 + (tid >> 6);
    if (row >= N) return;
    int lane = tid & 63;
    int e_off = lane >> 3;  // 0..7
    int fg = lane & 7;      // feats 2fg, 2fg+1
    int start = offs[row], c = cnt[row];
    float2 acc = make_float2(0.f, 0.f);
    for (int j = 0; j < c; j += 8) {
        int je = j + e_off;
        if (je < c) {
            int s = sorted_src[start + je];
            __half2 h = ((const __half2*)(h2 + (size_t)s * 16))[fg];
            float2 f = __half22float2(h);
            acc.x += f.x; acc.y += f.y;
        }
    }
#pragma unroll
    for (int m = 8; m <= 32; m <<= 1) {
        acc.x += __shfl_xor(acc.x, m);
        acc.y += __shfl_xor(acc.y, m);
    }
    if (e_off == 0) {
        float nd = norm_dst[row];
        float2 o;
        o.x = acc.x * nd + b2[fg * 2];
        o.y = acc.y * nd + b2[fg * 2 + 1];
        ((float2*)(out + (size_t)row * 16))[fg] = o;
    }
}

extern "C" void kernel_launch(void* const* d_in, const int* in_sizes, int n_in,
                              void* d_out, int out_size, void* d_ws, size_t ws_size,
                              hipStream_t stream) {
    const float* X  = (const float*)d_in[0];
    const int* src  = (const int*)d_in[1];
    const int* dst  = (const int*)d_in[2];
    const float* W1 = (const float*)d_in[3];
    const float* b1 = (const float*)d_in[4];
    const float* W2 = (const float*)d_in[5];
    const float* b2 = (const float*)d_in[6];
    float* out = (float*)d_out;

    const int N = in_sizes[0] / FEAT1;  // 50000
    const int E = in_sizes[1];          // 800000

    const int nrangeSide = (N + RBINS - 1) / RBINS;      // 8
    const int chunkE = (E + NCHUNK - 1) / NCHUNK;        // 32000
    const int nb = (N + 255) / 256;                      // 196 <= 256

    char* w = (char*)d_ws;
    int* hist_dst   = (int*)w;   w += N * 4;
    int* offs       = (int*)w;   w += N * 4;
    int* partials   = (int*)w;   w += 256 * 4;
    int* sorted_src = (int*)w;   w += E * 4;
    float* norm_src = (float*)w; w += N * 4;
    float* norm_dst = (float*)w; w += N * 4;
    int* partialS   = (int*)w;   w += (size_t)NCHUNK * N * 4;
    int* partialD   = (int*)w;   w += (size_t)NCHUNK * N * 4;
    __half* h1 = (__half*)w;     w += (size_t)N * 64 * 2;
    __half* t1 = (__half*)w;     w += (size_t)N * 64 * 2;
    __half* h2 = (__half*)w;     w += (size_t)N * 16 * 2;

    hist_part_kernel<<<NCHUNK * 2 * nrangeSide, 256, 0, stream>>>(src, dst, partialS, partialD,
                                                                  E, N, chunkE, nrangeSide);
    reduce_part_kernel<<<nb, 256, 0, stream>>>(partialS, partialD, hist_dst, norm_src, norm_dst,
                                               N, NCHUNK);
    scan1_kernel<<<nb, 256, 0, stream>>>(hist_dst, offs, partials, N);
    scan2_kernel<<<1, 256, 0, stream>>>(partials, nb);
    scan3_kernel<<<nb, 256, 0, stream>>>(offs, partials, N);
    reorder_kernel<<<NCHUNK * nrangeSide, 256, 0, stream>>>(src, dst, offs, partialD, sorted_src,
                                                            E, N, chunkE, nrangeSide);
    gemm1_kernel<<<(N + 15) / 16, 256, 0, stream>>>(X, W1, norm_src, h1, N);
    agg1_kernel<<<(N + 3) / 4, 256, 0, stream>>>(h1, sorted_src, offs, hist_dst, norm_dst, b1, t1, N);
    gemm2_kernel<<<(N + 15) / 16, 256, 0, stream>>>(t1, W2, norm_src, h2, N);
    agg2_kernel<<<(N + 3) / 4, 256, 0, stream>>>(h2, sorted_src, offs, hist_dst, norm_dst, b2, out, N);
}

// Round 5
// 232.602 us; speedup vs baseline: 1.4060x; 1.4060x over previous
//
#include <hip/hip_runtime.h>
#include <hip/hip_fp16.h>

#define FEAT1 64
#define FEAT2 16
#define NCHUNK_R 800   // radix chunks (<=1024 for scan_chunks)

// K1: per-chunk 256-bin coarse histograms of src>>8 and dst>>8
__global__ __launch_bounds__(256) void coarse_hist(const int* __restrict__ src,
                                                   const int* __restrict__ dst,
                                                   int* __restrict__ partS, int* __restrict__ partD,
                                                   int E, int chunkE) {
    __shared__ int hS[256], hD[256];
    int tid = threadIdx.x, chunk = blockIdx.x;
    hS[tid] = 0; hD[tid] = 0;
    __syncthreads();
    int e0 = chunk * chunkE, e1 = min(E, e0 + chunkE);
    for (int e = e0 + tid; e < e1; e += 256) {
        atomicAdd(&hS[src[e] >> 8], 1);
        atomicAdd(&hD[dst[e] >> 8], 1);
    }
    __syncthreads();
    partS[chunk * 256 + tid] = hS[tid];
    partD[chunk * 256 + tid] = hD[tid];
}

// K2: per-bin exclusive scan over chunks; grid 512 (side x 256 bins)
__global__ __launch_bounds__(256) void scan_chunks(int* partS, int* partD,
                                                   int* totS, int* totD, int nchunk) {
    __shared__ int sums[256];
    int tid = threadIdx.x;
    int bin = blockIdx.x & 255;
    int* part = (blockIdx.x >> 8) ? partD : partS;
    int* tot  = (blockIdx.x >> 8) ? totD : totS;
    int v[4];
    int base = tid * 4, local = 0;
#pragma unroll
    for (int j = 0; j < 4; j++) {
        int c = base + j;
        v[j] = (c < nchunk) ? part[c * 256 + bin] : 0;
        local += v[j];
    }
    sums[tid] = local;
    __syncthreads();
    for (int off = 1; off < 256; off <<= 1) {
        int t = (tid >= off) ? sums[tid - off] : 0;
        __syncthreads();
        sums[tid] += t;
        __syncthreads();
    }
    int run = sums[tid] - local;  // exclusive prefix
#pragma unroll
    for (int j = 0; j < 4; j++) {
        int c = base + j;
        if (c < nchunk) part[c * 256 + bin] = run;
        run += v[j];
    }
    if (tid == 255) tot[bin] = run;
}

// K3: exclusive scan of the 256 bin totals (both sides), one block
__global__ __launch_bounds__(256) void scan_bins(const int* __restrict__ totS,
                                                 const int* __restrict__ totD,
                                                 int* baseS, int* baseD) {
    __shared__ int s[256];
    int tid = threadIdx.x;
    int v = totS[tid];
    s[tid] = v;
    __syncthreads();
    for (int off = 1; off < 256; off <<= 1) {
        int t = (tid >= off) ? s[tid - off] : 0;
        __syncthreads();
        s[tid] += t;
        __syncthreads();
    }
    baseS[tid] = s[tid] - v;
    __syncthreads();
    v = totD[tid];
    s[tid] = v;
    __syncthreads();
    for (int off = 1; off < 256; off <<= 1) {
        int t = (tid >= off) ? s[tid - off] : 0;
        __syncthreads();
        s[tid] += t;
        __syncthreads();
    }
    baseD[tid] = s[tid] - v;
}

// K4: coarse partition with LDS cursors (no global atomics)
__global__ __launch_bounds__(256) void partition_coarse(const int* __restrict__ src,
                                                        const int* __restrict__ dst,
                                                        const int* __restrict__ partS,
                                                        const int* __restrict__ partD,
                                                        const int* __restrict__ baseS,
                                                        const int* __restrict__ baseD,
                                                        unsigned int* __restrict__ packD,
                                                        unsigned char* __restrict__ srcLow,
                                                        int E, int chunkE) {
    __shared__ int curS[256], curD[256];
    int tid = threadIdx.x, chunk = blockIdx.x;
    curS[tid] = baseS[tid] + partS[chunk * 256 + tid];
    curD[tid] = baseD[tid] + partD[chunk * 256 + tid];
    __syncthreads();
    int e0 = chunk * chunkE, e1 = min(E, e0 + chunkE);
    for (int e = e0 + tid; e < e1; e += 256) {
        int s = src[e], d = dst[e];
        int pD = atomicAdd(&curD[d >> 8], 1);
        packD[pD] = ((unsigned)(d & 255) << 16) | (unsigned)s;
        int pS = atomicAdd(&curS[s >> 8], 1);
        srcLow[pS] = (unsigned char)(s & 255);
    }
}

// K5: fine sort within each coarse dst bucket; emits offs/cnt/norm_dst + sorted_src
__global__ __launch_bounds__(256) void fine_dst(const unsigned int* __restrict__ packD,
                                                const int* __restrict__ baseD,
                                                const int* __restrict__ totD,
                                                int* __restrict__ sorted_src,
                                                int* __restrict__ offs, int* __restrict__ cnt,
                                                float* __restrict__ norm_dst, int N) {
    __shared__ int hist[256], pfx[256], cur[256];
    int tid = threadIdx.x, b = blockIdx.x;
    int lo = baseD[b], n = totD[b];
    hist[tid] = 0;
    __syncthreads();
    for (int i = lo + tid; i < lo + n; i += 256) atomicAdd(&hist[packD[i] >> 16], 1);
    __syncthreads();
    int v = hist[tid];
    pfx[tid] = v;
    __syncthreads();
    for (int off = 1; off < 256; off <<= 1) {
        int t = (tid >= off) ? pfx[tid - off] : 0;
        __syncthreads();
        pfx[tid] += t;
        __syncthreads();
    }
    int my = pfx[tid] - v;  // exclusive
    cur[tid] = lo + my;
    int node = b * 256 + tid;
    if (node < N) {
        offs[node] = lo + my;
        cnt[node] = v;
        norm_dst[node] = rsqrtf(fmaxf((float)v, 1.0f));
    }
    __syncthreads();
    for (int i = lo + tid; i < lo + n; i += 256) {
        unsigned p = packD[i];
        int pos = atomicAdd(&cur[p >> 16], 1);
        sorted_src[pos] = (int)(p & 0xFFFFu);
    }
}

// K6: fine src histogram per coarse bucket -> norm_src
__global__ __launch_bounds__(256) void fine_src(const unsigned char* __restrict__ srcLow,
                                                const int* __restrict__ baseS,
                                                const int* __restrict__ totS,
                                                float* __restrict__ norm_src, int N) {
    __shared__ int hist[256];
    int tid = threadIdx.x, b = blockIdx.x;
    int lo = baseS[b], n = totS[b];
    hist[tid] = 0;
    __syncthreads();
    for (int i = lo + tid; i < lo + n; i += 256) atomicAdd(&hist[srcLow[i]], 1);
    __syncthreads();
    int node = b * 256 + tid;
    if (node < N) norm_src[node] = rsqrtf(fmaxf((float)hist[tid], 1.0f));
}

// h1[row][c] = half((sum_k X[row][k]*W1[k][c]) * norm_src[row]); 16 rows/block
__global__ __launch_bounds__(256) void gemm1_kernel(const float* __restrict__ X,
                                                    const float* __restrict__ W1,
                                                    const float* __restrict__ norm_src,
                                                    __half* __restrict__ h1, int N) {
    __shared__ float sW[64 * 64];
    __shared__ float sX[16][64];
    int tid = threadIdx.x;
    int c = tid & 63, rs = tid >> 6;
    int row0 = blockIdx.x * 16;
    for (int i = tid; i < 64 * 64; i += 256) sW[i] = W1[i];
#pragma unroll
    for (int j = 0; j < 4; j++) {
        int r = rs + 4 * j;
        int row = row0 + r;
        sX[r][c] = (row < N) ? X[(size_t)row * 64 + c] : 0.f;
    }
    __syncthreads();
    float acc[4] = {0.f, 0.f, 0.f, 0.f};
#pragma unroll
    for (int k = 0; k < 64; k++) {
        float w = sW[k * 64 + c];
#pragma unroll
        for (int j = 0; j < 4; j++) acc[j] += sX[rs + 4 * j][k] * w;
    }
#pragma unroll
    for (int j = 0; j < 4; j++) {
        int row = row0 + rs + 4 * j;
        if (row < N) h1[(size_t)row * 64 + c] = __float2half(acc[j] * norm_src[row]);
    }
}

// gather-aggregate layer1 (fp16 rows, 4 edges/iter), fuse norm_dst+b1+relu
__global__ __launch_bounds__(256) void agg1_kernel(const __half* __restrict__ h1,
                                                   const int* __restrict__ sorted_src,
                                                   const int* __restrict__ offs,
                                                   const int* __restrict__ cnt,
                                                   const float* __restrict__ norm_dst,
                                                   const float* __restrict__ b1,
                                                   __half* __restrict__ t1, int N) {
    int tid = threadIdx.x;
    int row = blockIdx.x * 4 + (tid >> 6);
    if (row >= N) return;
    int lane = tid & 63;
    int e_off = lane >> 4;
    int fg = lane & 15;
    int start = offs[row], c = cnt[row];
    float4 acc = make_float4(0.f, 0.f, 0.f, 0.f);
    for (int j = 0; j < c; j += 4) {
        int je = j + e_off;
        if (je < c) {
            int s = sorted_src[start + je];
            uint2 u = ((const uint2*)(h1 + (size_t)s * 64))[fg];
            __half2 p0 = *reinterpret_cast<__half2*>(&u.x);
            __half2 p1 = *reinterpret_cast<__half2*>(&u.y);
            float2 f0 = __half22float2(p0), f1 = __half22float2(p1);
            acc.x += f0.x; acc.y += f0.y; acc.z += f1.x; acc.w += f1.y;
        }
    }
#pragma unroll
    for (int m = 16; m <= 32; m <<= 1) {
        acc.x += __shfl_xor(acc.x, m);
        acc.y += __shfl_xor(acc.y, m);
        acc.z += __shfl_xor(acc.z, m);
        acc.w += __shfl_xor(acc.w, m);
    }
    if (e_off == 0) {
        float nd = norm_dst[row];
        int f0 = fg * 4;
        float r0 = fmaxf(acc.x * nd + b1[f0 + 0], 0.f);
        float r1 = fmaxf(acc.y * nd + b1[f0 + 1], 0.f);
        float r2 = fmaxf(acc.z * nd + b1[f0 + 2], 0.f);
        float r3 = fmaxf(acc.w * nd + b1[f0 + 3], 0.f);
        __half2 o0 = __floats2half2_rn(r0, r1);
        __half2 o1 = __floats2half2_rn(r2, r3);
        uint2 u;
        u.x = *reinterpret_cast<unsigned int*>(&o0);
        u.y = *reinterpret_cast<unsigned int*>(&o1);
        ((uint2*)(t1 + (size_t)row * 64))[fg] = u;
    }
}

// h2[row][c] = half((sum_k t1[row][k]*W2[k][c]) * norm_src[row])
__global__ __launch_bounds__(256) void gemm2_kernel(const __half* __restrict__ t1,
                                                    const float* __restrict__ W2,
                                                    const float* __restrict__ norm_src,
                                                    __half* __restrict__ h2, int N) {
    __shared__ float sW[64 * 16];
    __shared__ float sT[16][65];
    int tid = threadIdx.x;
    int row0 = blockIdx.x * 16;
    for (int i = tid; i < 64 * 16; i += 256) sW[i] = W2[i];
    for (int l = tid; l < 16 * 32; l += 256) {
        int rr = l >> 5, kp = l & 31;
        int row = row0 + rr;
        float2 v = make_float2(0.f, 0.f);
        if (row < N) {
            __half2 h = ((const __half2*)(t1 + (size_t)row * 64))[kp];
            v = __half22float2(h);
        }
        sT[rr][kp * 2] = v.x;
        sT[rr][kp * 2 + 1] = v.y;
    }
    __syncthreads();
    int r = tid >> 4, c = tid & 15;
    int row = row0 + r;
    if (row < N) {
        float acc = 0.f;
#pragma unroll
        for (int k = 0; k < 64; k++) acc += sT[r][k] * sW[k * 16 + c];
        h2[(size_t)row * 16 + c] = __float2half(acc * norm_src[row]);
    }
}

// gather-aggregate layer2 (8 edges/iter) + epilogue
__global__ __launch_bounds__(256) void agg2_kernel(const __half* __restrict__ h2,
                                                   const int* __restrict__ sorted_src,
                                                   const int* __restrict__ offs,
                                                   const int* __restrict__ cnt,
                                                   const float* __restrict__ norm_dst,
                                                   const float* __restrict__ b2,
                                                   float* __restrict__ out, int N) {
    int tid = threadIdx.x;
    int row = blockIdx.x * 4 + (tid >> 6);
    if (row >= N) return;
    int lane = tid & 63;
    int e_off = lane >> 3;
    int fg = lane & 7;
    int start = offs[row], c = cnt[row];
    float2 acc = make_float2(0.f, 0.f);
    for (int j = 0; j < c; j += 8) {
        int je = j + e_off;
        if (je < c) {
            int s = sorted_src[start + je];
            __half2 h = ((const __half2*)(h2 + (size_t)s * 16))[fg];
            float2 f = __half22float2(h);
            acc.x += f.x; acc.y += f.y;
        }
    }
#pragma unroll
    for (int m = 8; m <= 32; m <<= 1) {
        acc.x += __shfl_xor(acc.x, m);
        acc.y += __shfl_xor(acc.y, m);
    }
    if (e_off == 0) {
        float nd = norm_dst[row];
        float2 o;
        o.x = acc.x * nd + b2[fg * 2];
        o.y = acc.y * nd + b2[fg * 2 + 1];
        ((float2*)(out + (size_t)row * 16))[fg] = o;
    }
}

extern "C" void kernel_launch(void* const* d_in, const int* in_sizes, int n_in,
                              void* d_out, int out_size, void* d_ws, size_t ws_size,
                              hipStream_t stream) {
    const float* X  = (const float*)d_in[0];
    const int* src  = (const int*)d_in[1];
    const int* dst  = (const int*)d_in[2];
    const float* W1 = (const float*)d_in[3];
    const float* b1 = (const float*)d_in[4];
    const float* W2 = (const float*)d_in[5];
    const float* b2 = (const float*)d_in[6];
    float* out = (float*)d_out;

    const int N = in_sizes[0] / FEAT1;  // 50000
    const int E = in_sizes[1];          // 800000
    const int chunkE = (E + NCHUNK_R - 1) / NCHUNK_R;  // 1000

    char* w = (char*)d_ws;
    int* partS = (int*)w;        w += (size_t)NCHUNK_R * 256 * 4;
    int* partD = (int*)w;        w += (size_t)NCHUNK_R * 256 * 4;
    int* totS  = (int*)w;        w += 256 * 4;
    int* totD  = (int*)w;        w += 256 * 4;
    int* baseS = (int*)w;        w += 256 * 4;
    int* baseD = (int*)w;        w += 256 * 4;
    unsigned int* packD = (unsigned int*)w; w += (size_t)E * 4;
    int* sorted_src = (int*)w;   w += (size_t)E * 4;
    int* offs = (int*)w;         w += (size_t)N * 4;
    int* cnt  = (int*)w;         w += (size_t)N * 4;
    float* norm_src = (float*)w; w += (size_t)N * 4;
    float* norm_dst = (float*)w; w += (size_t)N * 4;
    __half* h1 = (__half*)w;     w += (size_t)N * 64 * 2;
    __half* t1 = (__half*)w;     w += (size_t)N * 64 * 2;
    __half* h2 = (__half*)w;     w += (size_t)N * 16 * 2;
    unsigned char* srcLow = (unsigned char*)w; w += (size_t)E;

    coarse_hist<<<NCHUNK_R, 256, 0, stream>>>(src, dst, partS, partD, E, chunkE);
    scan_chunks<<<512, 256, 0, stream>>>(partS, partD, totS, totD, NCHUNK_R);
    scan_bins<<<1, 256, 0, stream>>>(totS, totD, baseS, baseD);
    partition_coarse<<<NCHUNK_R, 256, 0, stream>>>(src, dst, partS, partD, baseS, baseD,
                                                   packD, srcLow, E, chunkE);
    fine_dst<<<256, 256, 0, stream>>>(packD, baseD, totD, sorted_src, offs, cnt, norm_dst, N);
    fine_src<<<256, 256, 0, stream>>>(srcLow, baseS, totS, norm_src, N);
    gemm1_kernel<<<(N + 15) / 16, 256, 0, stream>>>(X, W1, norm_src, h1, N);
    agg1_kernel<<<(N + 3) / 4, 256, 0, stream>>>(h1, sorted_src, offs, cnt, norm_dst, b1, t1, N);
    gemm2_kernel<<<(N + 15) / 16, 256, 0, stream>>>(t1, W2, norm_src, h2, N);
    agg2_kernel<<<(N + 3) / 4, 256, 0, stream>>>(h2, sorted_src, offs, cnt, norm_dst, b2, out, N);
}

// Round 6
// 185.305 us; speedup vs baseline: 1.7649x; 1.2552x over previous
//
#include <hip/hip_runtime.h>
#include <hip/hip_fp16.h>

#define FEAT1 64
#define FEAT2 16
#define NCHUNK_R 800   // radix chunks

typedef _Float16 f16x8 __attribute__((ext_vector_type(8)));
typedef float f32x4 __attribute__((ext_vector_type(4)));

// ---------------- radix sort pipeline (unchanged from R5) ----------------

__global__ __launch_bounds__(256) void coarse_hist(const int* __restrict__ src,
                                                   const int* __restrict__ dst,
                                                   int* __restrict__ partS, int* __restrict__ partD,
                                                   int E, int chunkE) {
    __shared__ int hS[256], hD[256];
    int tid = threadIdx.x, chunk = blockIdx.x;
    hS[tid] = 0; hD[tid] = 0;
    __syncthreads();
    int e0 = chunk * chunkE, e1 = min(E, e0 + chunkE);
    for (int e = e0 + tid; e < e1; e += 256) {
        atomicAdd(&hS[src[e] >> 8], 1);
        atomicAdd(&hD[dst[e] >> 8], 1);
    }
    __syncthreads();
    partS[chunk * 256 + tid] = hS[tid];
    partD[chunk * 256 + tid] = hD[tid];
}

__global__ __launch_bounds__(256) void scan_chunks(int* partS, int* partD,
                                                   int* totS, int* totD, int nchunk) {
    __shared__ int sums[256];
    int tid = threadIdx.x;
    int bin = blockIdx.x & 255;
    int* part = (blockIdx.x >> 8) ? partD : partS;
    int* tot  = (blockIdx.x >> 8) ? totD : totS;
    int v[4];
    int base = tid * 4, local = 0;
#pragma unroll
    for (int j = 0; j < 4; j++) {
        int c = base + j;
        v[j] = (c < nchunk) ? part[c * 256 + bin] : 0;
        local += v[j];
    }
    sums[tid] = local;
    __syncthreads();
    for (int off = 1; off < 256; off <<= 1) {
        int t = (tid >= off) ? sums[tid - off] : 0;
        __syncthreads();
        sums[tid] += t;
        __syncthreads();
    }
    int run = sums[tid] - local;
#pragma unroll
    for (int j = 0; j < 4; j++) {
        int c = base + j;
        if (c < nchunk) part[c * 256 + bin] = run;
        run += v[j];
    }
    if (tid == 255) tot[bin] = run;
}

__global__ __launch_bounds__(256) void scan_bins(const int* __restrict__ totS,
                                                 const int* __restrict__ totD,
                                                 int* baseS, int* baseD) {
    __shared__ int s[256];
    int tid = threadIdx.x;
    int v = totS[tid];
    s[tid] = v;
    __syncthreads();
    for (int off = 1; off < 256; off <<= 1) {
        int t = (tid >= off) ? s[tid - off] : 0;
        __syncthreads();
        s[tid] += t;
        __syncthreads();
    }
    baseS[tid] = s[tid] - v;
    __syncthreads();
    v = totD[tid];
    s[tid] = v;
    __syncthreads();
    for (int off = 1; off < 256; off <<= 1) {
        int t = (tid >= off) ? s[tid - off] : 0;
        __syncthreads();
        s[tid] += t;
        __syncthreads();
    }
    baseD[tid] = s[tid] - v;
}

__global__ __launch_bounds__(256) void partition_coarse(const int* __restrict__ src,
                                                        const int* __restrict__ dst,
                                                        const int* __restrict__ partS,
                                                        const int* __restrict__ partD,
                                                        const int* __restrict__ baseS,
                                                        const int* __restrict__ baseD,
                                                        unsigned int* __restrict__ packD,
                                                        unsigned char* __restrict__ srcLow,
                                                        int E, int chunkE) {
    __shared__ int curS[256], curD[256];
    int tid = threadIdx.x, chunk = blockIdx.x;
    curS[tid] = baseS[tid] + partS[chunk * 256 + tid];
    curD[tid] = baseD[tid] + partD[chunk * 256 + tid];
    __syncthreads();
    int e0 = chunk * chunkE, e1 = min(E, e0 + chunkE);
    for (int e = e0 + tid; e < e1; e += 256) {
        int s = src[e], d = dst[e];
        int pD = atomicAdd(&curD[d >> 8], 1);
        packD[pD] = ((unsigned)(d & 255) << 16) | (unsigned)s;
        int pS = atomicAdd(&curS[s >> 8], 1);
        srcLow[pS] = (unsigned char)(s & 255);
    }
}

__global__ __launch_bounds__(256) void fine_dst(const unsigned int* __restrict__ packD,
                                                const int* __restrict__ baseD,
                                                const int* __restrict__ totD,
                                                int* __restrict__ sorted_src,
                                                int* __restrict__ offs, int* __restrict__ cnt,
                                                float* __restrict__ norm_dst, int N) {
    __shared__ int hist[256], pfx[256], cur[256];
    int tid = threadIdx.x, b = blockIdx.x;
    int lo = baseD[b], n = totD[b];
    hist[tid] = 0;
    __syncthreads();
    for (int i = lo + tid; i < lo + n; i += 256) atomicAdd(&hist[packD[i] >> 16], 1);
    __syncthreads();
    int v = hist[tid];
    pfx[tid] = v;
    __syncthreads();
    for (int off = 1; off < 256; off <<= 1) {
        int t = (tid >= off) ? pfx[tid - off] : 0;
        __syncthreads();
        pfx[tid] += t;
        __syncthreads();
    }
    int my = pfx[tid] - v;
    cur[tid] = lo + my;
    int node = b * 256 + tid;
    if (node < N) {
        offs[node] = lo + my;
        cnt[node] = v;
        norm_dst[node] = rsqrtf(fmaxf((float)v, 1.0f));
    }
    __syncthreads();
    for (int i = lo + tid; i < lo + n; i += 256) {
        unsigned p = packD[i];
        int pos = atomicAdd(&cur[p >> 16], 1);
        sorted_src[pos] = (int)(p & 0xFFFFu);
    }
}

__global__ __launch_bounds__(256) void fine_src(const unsigned char* __restrict__ srcLow,
                                                const int* __restrict__ baseS,
                                                const int* __restrict__ totS,
                                                float* __restrict__ norm_src, int N) {
    __shared__ int hist[256];
    int tid = threadIdx.x, b = blockIdx.x;
    int lo = baseS[b], n = totS[b];
    hist[tid] = 0;
    __syncthreads();
    for (int i = lo + tid; i < lo + n; i += 256) atomicAdd(&hist[srcLow[i]], 1);
    __syncthreads();
    int node = b * 256 + tid;
    if (node < N) norm_src[node] = rsqrtf(fmaxf((float)hist[tid], 1.0f));
}

// ---------------- MFMA GEMMs ----------------

// gemm1: h1[row][c] = f16( (X@W1)[row][c] * norm_src[row] )
// block = 256 = 4 waves, 128 rows/block, wave does 2 M-tiles of 16 rows
__global__ __launch_bounds__(256) void gemm1_kernel(const float* __restrict__ X,
                                                    const float* __restrict__ W1,
                                                    const float* __restrict__ norm_src,
                                                    __half* __restrict__ h1, int N) {
    __shared__ _Float16 sWt[64 * 72];       // Wt[n][k], stride 72 halfs (144 B, 16B-aligned rows)
    __shared__ float snorm[128];
    __shared__ _Float16 sTile[4][16 * 72];  // per-wave epilogue tile
    int tid = threadIdx.x;
    int row_blk = blockIdx.x * 128;
    for (int i = tid; i < 4096; i += 256) {
        int k = i >> 6, n = i & 63;
        sWt[n * 72 + k] = (_Float16)W1[i];
    }
    if (tid < 128) {
        int r = row_blk + tid;
        snorm[tid] = (r < N) ? norm_src[r] : 0.f;
    }
    __syncthreads();
    int wave = tid >> 6, lane = tid & 63;
    int m = lane & 15, quad = lane >> 4;
    f16x8 bfrag[4][2];
#pragma unroll
    for (int nt = 0; nt < 4; nt++)
#pragma unroll
        for (int kit = 0; kit < 2; kit++) {
            int n = nt * 16 + m;
            int k0 = kit * 32 + quad * 8;
            bfrag[nt][kit] = *(const f16x8*)&sWt[n * 72 + k0];
        }
    _Float16* tile = sTile[wave];
#pragma unroll
    for (int t = 0; t < 2; t++) {
        int row0 = row_blk + wave * 32 + t * 16;
        int row = row0 + m;
        bool inb = row < N;
        f32x4 acc[4] = {{0.f,0.f,0.f,0.f},{0.f,0.f,0.f,0.f},{0.f,0.f,0.f,0.f},{0.f,0.f,0.f,0.f}};
#pragma unroll
        for (int kit = 0; kit < 2; kit++) {
            f16x8 afrag;
            if (inb) {
                const float4* xp = (const float4*)(X + (size_t)row * 64 + kit * 32 + quad * 8);
                float4 x0 = xp[0], x1 = xp[1];
                afrag[0] = (_Float16)x0.x; afrag[1] = (_Float16)x0.y;
                afrag[2] = (_Float16)x0.z; afrag[3] = (_Float16)x0.w;
                afrag[4] = (_Float16)x1.x; afrag[5] = (_Float16)x1.y;
                afrag[6] = (_Float16)x1.z; afrag[7] = (_Float16)x1.w;
            } else {
#pragma unroll
                for (int j = 0; j < 8; j++) afrag[j] = (_Float16)0.f;
            }
#pragma unroll
            for (int nt = 0; nt < 4; nt++)
                acc[nt] = __builtin_amdgcn_mfma_f32_16x16x32_f16(afrag, bfrag[nt][kit], acc[nt], 0, 0, 0);
        }
        // D layout: row = quad*4+reg, col = nt*16+m
#pragma unroll
        for (int reg = 0; reg < 4; reg++) {
            int r = quad * 4 + reg;
            float nrm = snorm[wave * 32 + t * 16 + r];
#pragma unroll
            for (int nt = 0; nt < 4; nt++)
                tile[r * 72 + nt * 16 + m] = (_Float16)(acc[nt][reg] * nrm);
        }
        __syncthreads();
        int rr = lane >> 2, g = lane & 3;
        f16x8 p0 = *(const f16x8*)&tile[rr * 72 + g * 16];
        f16x8 p1 = *(const f16x8*)&tile[rr * 72 + g * 16 + 8];
        int orow = row0 + rr;
        if (orow < N) {
            *(f16x8*)((_Float16*)h1 + (size_t)orow * 64 + g * 16) = p0;
            *(f16x8*)((_Float16*)h1 + (size_t)orow * 64 + g * 16 + 8) = p1;
        }
        __syncthreads();
    }
}

// gemm2: h2[row][c] = f16( (t1@W2)[row][c] * norm_src[row] ), t1 fp16, N=16 cols
__global__ __launch_bounds__(256) void gemm2_kernel(const __half* __restrict__ t1h,
                                                    const float* __restrict__ W2,
                                                    const float* __restrict__ norm_src,
                                                    __half* __restrict__ h2, int N) {
    __shared__ _Float16 sWt[16 * 72];       // Wt2[n][k]
    __shared__ float snorm[128];
    __shared__ _Float16 sTile[4][16 * 20];  // [row][col] stride 20
    const _Float16* t1 = (const _Float16*)t1h;
    int tid = threadIdx.x;
    int row_blk = blockIdx.x * 128;
    for (int i = tid; i < 1024; i += 256) {
        int k = i >> 4, n = i & 15;
        sWt[n * 72 + k] = (_Float16)W2[i];
    }
    if (tid < 128) {
        int r = row_blk + tid;
        snorm[tid] = (r < N) ? norm_src[r] : 0.f;
    }
    __syncthreads();
    int wave = tid >> 6, lane = tid & 63;
    int m = lane & 15, quad = lane >> 4;
    f16x8 bfrag[2];
#pragma unroll
    for (int kit = 0; kit < 2; kit++)
        bfrag[kit] = *(const f16x8*)&sWt[m * 72 + kit * 32 + quad * 8];
    _Float16* tile = sTile[wave];
#pragma unroll
    for (int t = 0; t < 2; t++) {
        int row0 = row_blk + wave * 32 + t * 16;
        int row = row0 + m;
        bool inb = row < N;
        f32x4 acc = {0.f, 0.f, 0.f, 0.f};
#pragma unroll
        for (int kit = 0; kit < 2; kit++) {
            f16x8 afrag;
            if (inb) {
                afrag = *(const f16x8*)(t1 + (size_t)row * 64 + kit * 32 + quad * 8);
            } else {
#pragma unroll
                for (int j = 0; j < 8; j++) afrag[j] = (_Float16)0.f;
            }
            acc = __builtin_amdgcn_mfma_f32_16x16x32_f16(afrag, bfrag[kit], acc, 0, 0, 0);
        }
#pragma unroll
        for (int reg = 0; reg < 4; reg++) {
            int r = quad * 4 + reg;
            float nrm = snorm[wave * 32 + t * 16 + r];
            tile[r * 20 + m] = (_Float16)(acc[reg] * nrm);
        }
        __syncthreads();
        int rr = lane >> 2, c4 = lane & 3;
        _Float16 v0 = tile[rr * 20 + c4 * 4 + 0];
        _Float16 v1 = tile[rr * 20 + c4 * 4 + 1];
        _Float16 v2 = tile[rr * 20 + c4 * 4 + 2];
        _Float16 v3 = tile[rr * 20 + c4 * 4 + 3];
        int orow = row0 + rr;
        if (orow < N) {
            _Float16* op = (_Float16*)h2 + (size_t)orow * 16 + c4 * 4;
            op[0] = v0; op[1] = v1; op[2] = v2; op[3] = v3;
        }
        __syncthreads();
    }
}

// ---------------- aggregations (unchanged from R5) ----------------

__global__ __launch_bounds__(256) void agg1_kernel(const __half* __restrict__ h1,
                                                   const int* __restrict__ sorted_src,
                                                   const int* __restrict__ offs,
                                                   const int* __restrict__ cnt,
                                                   const float* __restrict__ norm_dst,
                                                   const float* __restrict__ b1,
                                                   __half* __restrict__ t1, int N) {
    int tid = threadIdx.x;
    int row = blockIdx.x * 4 + (tid >> 6);
    if (row >= N) return;
    int lane = tid & 63;
    int e_off = lane >> 4;
    int fg = lane & 15;
    int start = offs[row], c = cnt[row];
    float4 acc = make_float4(0.f, 0.f, 0.f, 0.f);
    for (int j = 0; j < c; j += 4) {
        int je = j + e_off;
        if (je < c) {
            int s = sorted_src[start + je];
            uint2 u = ((const uint2*)(h1 + (size_t)s * 64))[fg];
            __half2 p0 = *reinterpret_cast<__half2*>(&u.x);
            __half2 p1 = *reinterpret_cast<__half2*>(&u.y);
            float2 f0 = __half22float2(p0), f1 = __half22float2(p1);
            acc.x += f0.x; acc.y += f0.y; acc.z += f1.x; acc.w += f1.y;
        }
    }
#pragma unroll
    for (int m = 16; m <= 32; m <<= 1) {
        acc.x += __shfl_xor(acc.x, m);
        acc.y += __shfl_xor(acc.y, m);
        acc.z += __shfl_xor(acc.z, m);
        acc.w += __shfl_xor(acc.w, m);
    }
    if (e_off == 0) {
        float nd = norm_dst[row];
        int f0 = fg * 4;
        float r0 = fmaxf(acc.x * nd + b1[f0 + 0], 0.f);
        float r1 = fmaxf(acc.y * nd + b1[f0 + 1], 0.f);
        float r2 = fmaxf(acc.z * nd + b1[f0 + 2], 0.f);
        float r3 = fmaxf(acc.w * nd + b1[f0 + 3], 0.f);
        __half2 o0 = __floats2half2_rn(r0, r1);
        __half2 o1 = __floats2half2_rn(r2, r3);
        uint2 u;
        u.x = *reinterpret_cast<unsigned int*>(&o0);
        u.y = *reinterpret_cast<unsigned int*>(&o1);
        ((uint2*)(t1 + (size_t)row * 64))[fg] = u;
    }
}

__global__ __launch_bounds__(256) void agg2_kernel(const __half* __restrict__ h2,
                                                   const int* __restrict__ sorted_src,
                                                   const int* __restrict__ offs,
                                                   const int* __restrict__ cnt,
                                                   const float* __restrict__ norm_dst,
                                                   const float* __restrict__ b2,
                                                   float* __restrict__ out, int N) {
    int tid = threadIdx.x;
    int row = blockIdx.x * 4 + (tid >> 6);
    if (row >= N) return;
    int lane = tid & 63;
    int e_off = lane >> 3;
    int fg = lane & 7;
    int start = offs[row], c = cnt[row];
    float2 acc = make_float2(0.f, 0.f);
    for (int j = 0; j < c; j += 8) {
        int je = j + e_off;
        if (je < c) {
            int s = sorted_src[start + je];
            __half2 h = ((const __half2*)(h2 + (size_t)s * 16))[fg];
            float2 f = __half22float2(h);
            acc.x += f.x; acc.y += f.y;
        }
    }
#pragma unroll
    for (int m = 8; m <= 32; m <<= 1) {
        acc.x += __shfl_xor(acc.x, m);
        acc.y += __shfl_xor(acc.y, m);
    }
    if (e_off == 0) {
        float nd = norm_dst[row];
        float2 o;
        o.x = acc.x * nd + b2[fg * 2];
        o.y = acc.y * nd + b2[fg * 2 + 1];
        ((float2*)(out + (size_t)row * 16))[fg] = o;
    }
}

extern "C" void kernel_launch(void* const* d_in, const int* in_sizes, int n_in,
                              void* d_out, int out_size, void* d_ws, size_t ws_size,
                              hipStream_t stream) {
    const float* X  = (const float*)d_in[0];
    const int* src  = (const int*)d_in[1];
    const int* dst  = (const int*)d_in[2];
    const float* W1 = (const float*)d_in[3];
    const float* b1 = (const float*)d_in[4];
    const float* W2 = (const float*)d_in[5];
    const float* b2 = (const float*)d_in[6];
    float* out = (float*)d_out;

    const int N = in_sizes[0] / FEAT1;  // 50000
    const int E = in_sizes[1];          // 800000
    const int chunkE = (E + NCHUNK_R - 1) / NCHUNK_R;  // 1000

    char* w = (char*)d_ws;
    int* partS = (int*)w;        w += (size_t)NCHUNK_R * 256 * 4;
    int* partD = (int*)w;        w += (size_t)NCHUNK_R * 256 * 4;
    int* totS  = (int*)w;        w += 256 * 4;
    int* totD  = (int*)w;        w += 256 * 4;
    int* baseS = (int*)w;        w += 256 * 4;
    int* baseD = (int*)w;        w += 256 * 4;
    unsigned int* packD = (unsigned int*)w; w += (size_t)E * 4;
    int* sorted_src = (int*)w;   w += (size_t)E * 4;
    int* offs = (int*)w;         w += (size_t)N * 4;
    int* cnt  = (int*)w;         w += (size_t)N * 4;
    float* norm_src = (float*)w; w += (size_t)N * 4;
    float* norm_dst = (float*)w; w += (size_t)N * 4;
    __half* h1 = (__half*)w;     w += (size_t)N * 64 * 2;
    __half* t1 = (__half*)w;     w += (size_t)N * 64 * 2;
    __half* h2 = (__half*)w;     w += (size_t)N * 16 * 2;
    unsigned char* srcLow = (unsigned char*)w; w += (size_t)E;

    coarse_hist<<<NCHUNK_R, 256, 0, stream>>>(src, dst, partS, partD, E, chunkE);
    scan_chunks<<<512, 256, 0, stream>>>(partS, partD, totS, totD, NCHUNK_R);
    scan_bins<<<1, 256, 0, stream>>>(totS, totD, baseS, baseD);
    partition_coarse<<<NCHUNK_R, 256, 0, stream>>>(src, dst, partS, partD, baseS, baseD,
                                                   packD, srcLow, E, chunkE);
    fine_dst<<<256, 256, 0, stream>>>(packD, baseD, totD, sorted_src, offs, cnt, norm_dst, N);
    fine_src<<<256, 256, 0, stream>>>(srcLow, baseS, totS, norm_src, N);
    gemm1_kernel<<<(N + 127) / 128, 256, 0, stream>>>(X, W1, norm_src, h1, N);
    agg1_kernel<<<(N + 3) / 4, 256, 0, stream>>>(h1, sorted_src, offs, cnt, norm_dst, b1, t1, N);
    gemm2_kernel<<<(N + 127) / 128, 256, 0, stream>>>(t1, W2, norm_src, h2, N);
    agg2_kernel<<<(N + 3) / 4, 256, 0, stream>>>(h2, sorted_src, offs, cnt, norm_dst, b2, out, N);
}